// Round 1
// 509.970 us; speedup vs baseline: 1.0690x; 1.0690x over previous
//
#include <hip/hip_runtime.h>
#include <math.h>

constexpr int BATCH = 4;
constexpr int SEQ   = 2048;
constexpr int HID   = 2048;
constexpr int NHEAD = 8;
constexpr int HD    = 256;
constexpr int QKVN  = (NHEAD + 2) * HD;          // 2560
constexpr float SCL = 0.0625f;                   // 256^-0.5

typedef __bf16 bf16_t;
typedef __bf16 bf16x8 __attribute__((ext_vector_type(8)));
typedef float  f32x4  __attribute__((ext_vector_type(4)));

__device__ __forceinline__ f32x4 zero4() {
  f32x4 z; z[0] = 0.f; z[1] = 0.f; z[2] = 0.f; z[3] = 0.f; return z;
}

__device__ __forceinline__ f32x4 mfma16(bf16x8 a, bf16x8 b, f32x4 c) {
  return __builtin_amdgcn_mfma_f32_16x16x32_bf16(a, b, c, 0, 0, 0);
}

// async global->LDS, 16B per lane. lds must be wave-uniform base; HW adds lane*16.
__device__ __forceinline__ void gl2lds16(const void* g, void* lds) {
  typedef __attribute__((address_space(1))) void* gp_t;
  typedef __attribute__((address_space(3))) void* lp_t;
  __builtin_amdgcn_global_load_lds((gp_t)(size_t)g,
                                   (lp_t)(unsigned int)(size_t)lds, 16, 0, 0);
}

__device__ __forceinline__ float rmax16(float v) {
#pragma unroll
  for (int o = 1; o < 16; o <<= 1) v = fmaxf(v, __shfl_xor(v, o));
  return v;
}
__device__ __forceinline__ float rsum16(float v) {
#pragma unroll
  for (int o = 1; o < 16; o <<= 1) v += __shfl_xor(v, o);
  return v;
}

// ---------- fp32 -> bf16 bulk convert (8 elems/thread) ----------
__global__ __launch_bounds__(256)
void cvt_bf16_kernel(const float* __restrict__ in, bf16_t* __restrict__ out) {
  const int i = blockIdx.x * 256 + threadIdx.x;
  const float4 a = ((const float4*)in)[i * 2];
  const float4 b = ((const float4*)in)[i * 2 + 1];
  bf16x8 o;
  o[0] = (bf16_t)a.x; o[1] = (bf16_t)a.y; o[2] = (bf16_t)a.z; o[3] = (bf16_t)a.w;
  o[4] = (bf16_t)b.x; o[5] = (bf16_t)b.y; o[6] = (bf16_t)b.z; o[7] = (bf16_t)b.w;
  ((bf16x8*)out)[i] = o;
}

// ---------- w[K][N] fp32 -> wT[N][K] bf16, 64x64 tiles ----------
__global__ __launch_bounds__(256)
void transw_kernel(const float* __restrict__ w, bf16_t* __restrict__ wT, int K, int N) {
  __shared__ __align__(16) bf16_t tile[64][72];
  const int n0 = blockIdx.x * 64, k0 = blockIdx.y * 64;
  const int t = threadIdx.x, rr = t >> 3, c8 = (t & 7) * 8;
#pragma unroll
  for (int it = 0; it < 2; ++it) {
    const int r = rr + it * 32;
    const float4* p = (const float4*)(w + (size_t)(k0 + r) * N + n0 + c8);
    const float4 a = p[0], b = p[1];
    bf16x8 o;
    o[0] = (bf16_t)a.x; o[1] = (bf16_t)a.y; o[2] = (bf16_t)a.z; o[3] = (bf16_t)a.w;
    o[4] = (bf16_t)b.x; o[5] = (bf16_t)b.y; o[6] = (bf16_t)b.z; o[7] = (bf16_t)b.w;
    *(bf16x8*)&tile[r][c8] = o;
  }
  __syncthreads();
#pragma unroll
  for (int it = 0; it < 2; ++it) {
    const int rn = rr + it * 32;
    bf16x8 o;
#pragma unroll
    for (int j = 0; j < 8; ++j) o[j] = tile[c8 + j][rn];
    *(bf16x8*)&wT[(size_t)(n0 + rn) * K + k0 + c8] = o;
  }
}

// ---------- MFMA GEMM: C[M][N] = A[M][K] * BT[N][K]^T  (m97 recipe) ----------
template <typename TC>
__global__ __launch_bounds__(256)
void gemm_bt_kernel(const bf16_t* __restrict__ A, const bf16_t* __restrict__ BT,
                    TC* __restrict__ C, int M, int N, int K) {
  __shared__ __align__(16) bf16_t As[128 * 32];
  __shared__ __align__(16) bf16_t Bs[128 * 32];
  const int tid = threadIdx.x;
  const int lane = tid & 63, w = tid >> 6;
  const int quad = lane >> 4, l15 = lane & 15;
  const int bm = blockIdx.y * 128, bn = blockIdx.x * 128;
  const int wm = (w & 1) * 64, wn = (w >> 1) * 64;
  const int r0 = tid >> 2, c0 = tid & 3;   // staging: 4 chunks of 16B per 32-elem row

  f32x4 acc[4][4];
#pragma unroll
  for (int mt = 0; mt < 4; ++mt)
#pragma unroll
    for (int nt = 0; nt < 4; ++nt) acc[mt][nt] = zero4();

  for (int k0 = 0; k0 < K; k0 += 32) {
#pragma unroll
    for (int i = 0; i < 2; ++i) {
      const int r = r0 + i * 64;
      const int cg = (c0 ^ (r & 3)) << 3;   // XOR-swizzled source column
      gl2lds16(A + (size_t)(bm + r) * K + k0 + cg, &As[(i * 256 + w * 64) * 8]);
      gl2lds16(BT + (size_t)(bn + r) * K + k0 + cg, &Bs[(i * 256 + w * 64) * 8]);
    }
    __syncthreads();
    bf16x8 af[4], bf[4];
#pragma unroll
    for (int mt = 0; mt < 4; ++mt) {
      const int row = wm + mt * 16 + l15;
      af[mt] = *(const bf16x8*)&As[row * 32 + ((quad ^ (row & 3)) << 3)];
    }
#pragma unroll
    for (int nt = 0; nt < 4; ++nt) {
      const int row = wn + nt * 16 + l15;
      bf[nt] = *(const bf16x8*)&Bs[row * 32 + ((quad ^ (row & 3)) << 3)];
    }
#pragma unroll
    for (int mt = 0; mt < 4; ++mt)
#pragma unroll
      for (int nt = 0; nt < 4; ++nt)
        acc[mt][nt] = mfma16(af[mt], bf[nt], acc[mt][nt]);
    __syncthreads();
  }

#pragma unroll
  for (int mt = 0; mt < 4; ++mt)
#pragma unroll
    for (int nt = 0; nt < 4; ++nt)
#pragma unroll
      for (int r = 0; r < 4; ++r) {
        const int row = bm + wm + mt * 16 + quad * 4 + r;
        const int col = bn + wn + nt * 16 + l15;
        C[(size_t)row * N + col] = (TC)acc[mt][nt][r];
      }
}

// ---------- RoPE cos/sin table: tab[s][i] = (cos, sin) ----------
__global__ __launch_bounds__(128)
void rope_table_kernel(const int* __restrict__ pos, float2* __restrict__ tab) {
  const int s = blockIdx.x, i = threadIdx.x;
  const float inv_freq = powf(10000.0f, -(float)i / 128.0f);
  const float ang = (float)pos[s] * inv_freq;
  float sn, cs;
  sincosf(ang, &sn, &cs);
  tab[s * 128 + i] = make_float2(cs, sn);
}

// ---------- RoPE apply, table-driven, bf16x8 vectorized ----------
// 16 (bs) rows per block, 16 threads per row, 8 elems per thread.
__global__ __launch_bounds__(256)
void rope_kernel(const float2* __restrict__ tab, bf16_t* __restrict__ qkv) {
  const int bs = blockIdx.x * 16 + (threadIdx.x >> 4);
  const int h  = blockIdx.y;
  const int i0 = (threadIdx.x & 15) * 8;
  const int s  = bs & (SEQ - 1);
  const size_t base = (size_t)bs * QKVN + (size_t)h * HD;
  bf16x8 a = *(const bf16x8*)&qkv[base + i0];
  bf16x8 b = *(const bf16x8*)&qkv[base + 128 + i0];
  bf16x8 oa, ob;
#pragma unroll
  for (int j = 0; j < 8; ++j) {
    const float2 t = tab[s * 128 + i0 + j];
    const float x1 = (float)a[j], x2 = (float)b[j];
    oa[j] = (bf16_t)(x1 * t.x - x2 * t.y);
    ob[j] = (bf16_t)(x2 * t.x + x1 * t.y);
  }
  *(bf16x8*)&qkv[base + i0]       = oa;
  *(bf16x8*)&qkv[base + 128 + i0] = ob;
}

// ---------- V transpose: qkv v-part [s][d] -> Vt[b][d][s] ----------
__global__ __launch_bounds__(256)
void vtrans_kernel(const bf16_t* __restrict__ qkv, bf16_t* __restrict__ Vt) {
  __shared__ __align__(16) bf16_t tile[64][72];
  const int s0 = blockIdx.x * 64, d0 = blockIdx.y * 64, b = blockIdx.z;
  const int t = threadIdx.x, rr = t >> 3, c8 = (t & 7) * 8;
#pragma unroll
  for (int it = 0; it < 2; ++it) {
    const int r = rr + it * 32;
    *(bf16x8*)&tile[r][c8] =
        *(const bf16x8*)&qkv[(size_t)(b * SEQ + s0 + r) * QKVN + 2304 + d0 + c8];
  }
  __syncthreads();
#pragma unroll
  for (int it = 0; it < 2; ++it) {
    const int dd = rr + it * 32;
    bf16x8 o;
#pragma unroll
    for (int j = 0; j < 8; ++j) o[j] = tile[c8 + j][dd];
    *(bf16x8*)&Vt[(size_t)(b * HD + d0 + dd) * SEQ + s0 + c8] = o;
  }
}

// ---------- flash attention, MQA-shared K/V staging, double-buffered ----------
// Block: 512 threads = 8 waves, wave w = head w. All waves share one K/V tile.
// Each block processes the complementary q-tile pair (qt, 127-qt) sequentially
// -> uniform ~33 K-tile iterations per block, 256 blocks = 1 per CU.
// 2-phase pipeline (T3 minimum): stage tile kt+1 into buf^1 while computing
// tile kt from buf; single barrier per tile (its implicit vmcnt(0) drain is
// where the prefetch completes, overlapped with compute).
__global__ __launch_bounds__(512)
void attn_kernel(const bf16_t* __restrict__ qkv, const bf16_t* __restrict__ Vt,
                 bf16_t* __restrict__ O) {
  __shared__ __align__(16) bf16_t Ks[2][64 * 256];    // [key][d], chunk-swizzled (2x32 KB)
  __shared__ __align__(16) bf16_t Vts[2][256 * 64];   // [d][key], chunk-swizzled (2x32 KB)
  __shared__ __align__(16) bf16_t Pl[8][16][72];      // per-wave P, padded rows (18.4 KB)

  const int tid = threadIdx.x, w = tid >> 6, lane = tid & 63;
  const int quad = lane >> 4, l15 = lane & 15;
  const int b = blockIdx.x >> 6;                      // 4 batches x 64 pair-groups
  const int qtR = blockIdx.x & 63;
  const int h = w;

  // staging decomposition (512 threads)
  const int krow_base = w * 2 + (lane >> 5);          // + i*16 -> key row 0..63
  const int kcol = lane & 31;                         // 16B chunk within 256-d row
  const int vrow_base = w * 8 + (lane >> 3);          // + i*64 -> d row 0..255
  const int vcol = lane & 7;                          // 16B chunk within 64-key row

  const bf16_t* kbase0 = qkv + (size_t)(b * SEQ) * QKVN + 2048;
  const bf16_t* vbase0 = Vt + (size_t)b * HD * SEQ;

  auto stage = [&](int kt, int buf) {
    const bf16_t* kbase = kbase0 + (size_t)(kt * 64) * QKVN;
#pragma unroll
    for (int i = 0; i < 4; ++i) {
      const int r = i * 16 + krow_base;
      gl2lds16(kbase + (size_t)r * QKVN + ((kcol ^ (r & 31)) << 3),
               &Ks[buf][(i * 512 + w * 64) * 8]);
    }
    const bf16_t* vbase = vbase0 + kt * 64;
#pragma unroll
    for (int i = 0; i < 4; ++i) {
      const int r = i * 64 + vrow_base;
      gl2lds16(vbase + (size_t)r * SEQ + ((vcol ^ (r & 7)) << 3),
               &Vts[buf][(i * 512 + w * 64) * 8]);
    }
  };

  for (int phase = 0; phase < 2; ++phase) {
    const int qt = phase ? (127 - qtR) : qtR;
    const int q0 = qt * 16;

    // Q fragments (A-layout: m = l15, k = quad*8+j)
    bf16x8 qf[8];
    const bf16_t* qp =
        qkv + (size_t)(b * SEQ + q0 + l15) * QKVN + (size_t)h * HD + quad * 8;
#pragma unroll
    for (int ks = 0; ks < 8; ++ks) qf[ks] = *(const bf16x8*)(qp + ks * 32);

    float mrun[4], lrun[4];
    f32x4 of[16];
#pragma unroll
    for (int r = 0; r < 4; ++r) { mrun[r] = -3e38f; lrun[r] = 0.f; }
#pragma unroll
    for (int dt = 0; dt < 16; ++dt) of[dt] = zero4();

    const int ntiles = q0 / 64 + 1;
    int cur = 0;
    stage(0, 0);
    __syncthreads();                          // prologue drain

    for (int kt = 0; kt < ntiles; ++kt) {
      // ---- issue next tile's stage first: latency hides under compute ----
      if (kt + 1 < ntiles) stage(kt + 1, cur ^ 1);

      const bf16_t* ksb = Ks[cur];
      const bf16_t* vsb = Vts[cur];

      // ---- S = Q K^T ----
      f32x4 sf[4];
#pragma unroll
      for (int nt = 0; nt < 4; ++nt) {
        f32x4 acc = zero4();
        const int row = nt * 16 + l15;
#pragma unroll
        for (int ks = 0; ks < 8; ++ks) {
          const int j = ks * 4 + quad;
          const bf16x8 kf = *(const bf16x8*)&ksb[row * 256 + ((j ^ (row & 31)) << 3)];
          acc = mfma16(qf[ks], kf, acc);
        }
        sf[nt] = acc;
      }

      // ---- scale + (diagonal-tile-only) causal mask + row max ----
      const bool lastTile = (kt == ntiles - 1);
      float mx[4];
#pragma unroll
      for (int r = 0; r < 4; ++r) {
        const int qg = q0 + quad * 4 + r;
        float v = -3e38f;
#pragma unroll
        for (int nt = 0; nt < 4; ++nt) {
          float s = sf[nt][r] * SCL;
          if (lastTile) {
            const int kg = kt * 64 + nt * 16 + l15;
            if (kg > qg) s = -3e38f;
          }
          sf[nt][r] = s;
          v = fmaxf(v, s);
        }
        mx[r] = rmax16(v);
      }

      // ---- defer-max (T13): rescale only when max grew by > 8 ----
      float g = 0.f;
#pragma unroll
      for (int r = 0; r < 4; ++r) g = fmaxf(g, mx[r] - mrun[r]);
      const bool resc = !__all(g <= 8.0f);
      f32x4 av;
      if (resc) {
#pragma unroll
        for (int r = 0; r < 4; ++r) {
          const float mn = fmaxf(mrun[r], mx[r]);
          av[r] = __expf(mrun[r] - mn);
          mrun[r] = mn;
          lrun[r] *= av[r];
        }
      }

      // ---- P = exp(S - m), row sums ----
#pragma unroll
      for (int r = 0; r < 4; ++r) {
        float sum = 0.f;
#pragma unroll
        for (int nt = 0; nt < 4; ++nt) {
          const float pv = __expf(sf[nt][r] - mrun[r]);
          Pl[w][quad * 4 + r][nt * 16 + l15] = (bf16_t)pv;
          sum += pv;
        }
        lrun[r] += rsum16(sum);
      }
      if (resc) {
#pragma unroll
        for (int dt = 0; dt < 16; ++dt) of[dt] *= av;
      }
      __asm__ volatile("s_waitcnt lgkmcnt(0)" ::: "memory");  // wave-local P handoff

      // ---- O += P V ----
      bf16x8 pa[2];
#pragma unroll
      for (int k2 = 0; k2 < 2; ++k2)
        pa[k2] = *(const bf16x8*)&Pl[w][l15][k2 * 32 + quad * 8];
#pragma unroll
      for (int dt = 0; dt < 16; ++dt) {
        const int row = dt * 16 + l15;
#pragma unroll
        for (int k2 = 0; k2 < 2; ++k2) {
          const int j = k2 * 4 + quad;
          const bf16x8 vf = *(const bf16x8*)&vsb[row * 64 + ((j ^ (row & 7)) << 3)];
          of[dt] = mfma16(pa[k2], vf, of[dt]);
        }
      }

      __syncthreads();   // prefetch of buf^1 complete; all reads of buf done
      cur ^= 1;
    }

    // ---- epilogue: O /= l, store bf16 [b][s][h*HD+d] ----
    f32x4 iv;
#pragma unroll
    for (int r = 0; r < 4; ++r) iv[r] = 1.0f / lrun[r];
#pragma unroll
    for (int dt = 0; dt < 16; ++dt) {
      const f32x4 o = of[dt] * iv;
#pragma unroll
      for (int r = 0; r < 4; ++r)
        O[(size_t)(b * SEQ + q0 + quad * 4 + r) * HID + (size_t)h * HD + dt * 16 + l15] =
            (bf16_t)o[r];
    }
  }
}

// ---------- launch ----------
extern "C" void kernel_launch(void* const* d_in, const int* in_sizes, int n_in,
                              void* d_out, int out_size, void* d_ws, size_t ws_size,
                              hipStream_t stream) {
  const float* hidden  = (const float*)d_in[0];
  const int* positions = (const int*)d_in[1];
  const float* w_qkv   = (const float*)d_in[2];
  const float* w_o     = (const float*)d_in[3];
  float* out           = (float*)d_out;

  char* ws = (char*)d_ws;
  bf16_t* hiddenB = (bf16_t*)ws; ws += (size_t)8192 * 2048 * 2;   // 33.5 MB
  bf16_t* wqkvT   = (bf16_t*)ws; ws += (size_t)2560 * 2048 * 2;   // 10.5 MB
  bf16_t* woT     = (bf16_t*)ws; ws += (size_t)2048 * 2048 * 2;   //  8.4 MB
  bf16_t* qkvB    = (bf16_t*)ws; ws += (size_t)8192 * 2560 * 2;   // 41.9 MB
  bf16_t* VtB     = (bf16_t*)ws; ws += (size_t)4 * 256 * 2048 * 2;//  4.2 MB
  bf16_t* attnB   = (bf16_t*)ws;                                  // 33.5 MB

  // rope table aliases the attnB region (2 MB << 33.5 MB); attnB is written
  // only later by attn_kernel, after the table has been consumed.
  float2* ropeTab = (float2*)attnB;

  cvt_bf16_kernel<<<8192, 256, 0, stream>>>(hidden, hiddenB);
  transw_kernel<<<dim3(QKVN / 64, HID / 64), 256, 0, stream>>>(w_qkv, wqkvT, HID, QKVN);
  transw_kernel<<<dim3(HID / 64, HID / 64), 256, 0, stream>>>(w_o, woT, HID, HID);
  rope_table_kernel<<<SEQ, 128, 0, stream>>>(positions, ropeTab);

  gemm_bt_kernel<bf16_t><<<dim3(QKVN / 128, 64), 256, 0, stream>>>
      (hiddenB, wqkvT, qkvB, 8192, QKVN, HID);

  rope_kernel<<<dim3(BATCH * SEQ / 16, 9), 256, 0, stream>>>(ropeTab, qkvB);
  vtrans_kernel<<<dim3(SEQ / 64, HD / 64, BATCH), 256, 0, stream>>>(qkvB, VtB);

  attn_kernel<<<256, 512, 0, stream>>>(qkvB, VtB, attnB);

  gemm_bt_kernel<float><<<dim3(HID / 128, 64), 256, 0, stream>>>
      (attnB, woT, out, 8192, HID, HID);
}